// Round 2
// baseline (933.894 us; speedup 1.0000x reference)
//
#include <hip/hip_runtime.h>
#include <hip/hip_bf16.h>
#include <math.h>

#define NA 1024
#define NB 1024
#define DS 512
#define RANK 32
#define DP 128
#define NRBF 64
#define KTOT 96           // RANK + NRBF
#define SMEM_BYTES ((KTOT * DP + 64 * KTOT) * 4)   // U[96][128] + V[64][96] = 73728 B

// ---------------- Kernel A: row-major projection  out[i][r] = b[r] + sum_d in[i][d]*W[r][d]
__global__ void proj_kernel(const float* __restrict__ in,
                            const float* __restrict__ W,
                            const float* __restrict__ b,
                            float* __restrict__ out) {
    int t = threadIdx.x;
    int r = t & 31;                      // 0..31
    int row = blockIdx.x * 8 + (t >> 5); // 8 rows per block
    const float4* in4 = (const float4*)(in + (size_t)row * DS);
    const float4* w4  = (const float4*)(W + (size_t)r * DS);
    float s = 0.f;
#pragma unroll 8
    for (int d = 0; d < DS / 4; ++d) {
        float4 a = in4[d], w = w4[d];
        s = fmaf(a.x, w.x, s);
        s = fmaf(a.y, w.y, s);
        s = fmaf(a.z, w.z, s);
        s = fmaf(a.w, w.w, s);
    }
    out[row * RANK + r] = s + b[r];
}

// ---------------- Kernel C: per-i block, fused outer-product + RBF + LayerNorm
__global__ void __launch_bounds__(256, 2) pair_kernel(
    const float* __restrict__ left, const float* __restrict__ right,
    const float* __restrict__ x_a, const float* __restrict__ x_b,
    const float* __restrict__ W_outer, const float* __restrict__ b_outer,
    const float* __restrict__ W_dist, const float* __restrict__ b_dist,
    const float* __restrict__ gamma, const float* __restrict__ beta,
    const float* __restrict__ centers, float* __restrict__ out) {
    extern __shared__ float smem[];
    float* U = smem;                 // [96][128]  rows 0..31: lw_t, rows 32..95: W_dist^T
    float* V = smem + KTOT * DP;     // [64][96]   cols 0..31: right, 32..95: rbf
    const int t = threadIdx.x;
    const int i = blockIdx.x;

    // ---- stage U rows 0..31:  U[s][p] = sum_r left[i][r] * W_outer[p][r*32+s]
    float lrow[RANK];
#pragma unroll
    for (int r = 0; r < RANK; ++r) lrow[r] = left[i * RANK + r];
    for (int o = t; o < DP * RANK; o += 256) {
        int p = o >> 5, s = o & 31;
        float acc = 0.f;
        const float* wrow = W_outer + (size_t)p * (RANK * RANK) + s;
#pragma unroll
        for (int r = 0; r < RANK; ++r)
            acc = fmaf(lrow[r], wrow[r * RANK], acc);
        U[s * DP + p] = acc;
    }
    // ---- stage U rows 32..95:  U[32+k][p] = W_dist[p][k]   (coalesced read, conflicted LDS
    //      write is once-per-block and negligible)
    for (int o = t; o < DP * NRBF; o += 256) {
        int p = o >> 6, k = o & 63;
        U[(RANK + k) * DP + p] = W_dist[o];
    }

    // per-thread constants
    const int pg = t & 31;   // p-quad index: p = 4*pg .. 4*pg+3
    const int jg = t >> 5;   // j-group 0..7, each owns 8 j
    float4 g4  = ((const float4*)gamma)[pg];
    float4 be4 = ((const float4*)beta)[pg];
    float4 bo4 = ((const float4*)b_outer)[pg];
    float4 bd4 = ((const float4*)b_dist)[pg];
    float4 binit = make_float4(bo4.x + bd4.x, bo4.y + bd4.y, bo4.z + bd4.z, bo4.w + bd4.w);
    float xa0 = x_a[i * 3 + 0], xa1 = x_a[i * 3 + 1], xa2 = x_a[i * 3 + 2];
    float ck = centers[t & 63];
    __syncthreads();

    for (int it = 0; it < 16; ++it) {
        int jb = it << 6;   // 64-j tile base
        if (it) __syncthreads();   // previous compute done before V rebuild
        // ---- V right part
        for (int o = t; o < 64 * RANK; o += 256) {
            int jl = o >> 5, s = o & 31;
            V[jl * KTOT + s] = right[(jb + jl) * RANK + s];
        }
        // ---- V rbf part: lane k computes one exp per j
        {
            int k = t & 63;
            int jsub = t >> 6;   // 0..3
#pragma unroll
            for (int pass = 0; pass < 16; ++pass) {
                int jl = jsub + (pass << 2);
                int j = jb + jl;
                float dx = xa0 - x_b[j * 3 + 0];
                float dy = xa1 - x_b[j * 3 + 1];
                float dz = xa2 - x_b[j * 3 + 2];
                float d = sqrtf(fmaf(dx, dx, fmaf(dy, dy, dz * dz)));
                float u = d - ck;
                V[jl * KTOT + RANK + k] = __expf(-10.24f * u * u);  // 1/sigma = (64/20)^2
            }
        }
        __syncthreads();

        // ---- register-tiled contraction: acc[8 j][4 p]
        float4 acc[8];
#pragma unroll
        for (int jj = 0; jj < 8; ++jj) acc[jj] = binit;

        for (int q0 = 0; q0 < KTOT; q0 += 4) {
            float4 u0 = *(const float4*)(U + (q0 + 0) * DP + (pg << 2));
            float4 u1 = *(const float4*)(U + (q0 + 1) * DP + (pg << 2));
            float4 u2 = *(const float4*)(U + (q0 + 2) * DP + (pg << 2));
            float4 u3 = *(const float4*)(U + (q0 + 3) * DP + (pg << 2));
#pragma unroll
            for (int jj = 0; jj < 8; ++jj) {
                float4 v = *(const float4*)(V + ((jg << 3) + jj) * KTOT + q0);
                acc[jj].x = fmaf(u0.x, v.x, fmaf(u1.x, v.y, fmaf(u2.x, v.z, fmaf(u3.x, v.w, acc[jj].x))));
                acc[jj].y = fmaf(u0.y, v.x, fmaf(u1.y, v.y, fmaf(u2.y, v.z, fmaf(u3.y, v.w, acc[jj].y))));
                acc[jj].z = fmaf(u0.z, v.x, fmaf(u1.z, v.y, fmaf(u2.z, v.z, fmaf(u3.z, v.w, acc[jj].z))));
                acc[jj].w = fmaf(u0.w, v.x, fmaf(u1.w, v.y, fmaf(u2.w, v.z, fmaf(u3.w, v.w, acc[jj].w))));
            }
        }

        // ---- LayerNorm over p (128 values = 32 lanes x 4) + store
#pragma unroll
        for (int jj = 0; jj < 8; ++jj) {
            float4 a = acc[jj];
            float s1 = a.x + a.y + a.z + a.w;
            float s2 = a.x * a.x + a.y * a.y + a.z * a.z + a.w * a.w;
#pragma unroll
            for (int m = 1; m <= 16; m <<= 1) {
                s1 += __shfl_xor(s1, m);
                s2 += __shfl_xor(s2, m);
            }
            float mean = s1 * (1.f / 128.f);
            float var = fmaf(s2, 1.f / 128.f, -mean * mean);
            float rstd = rsqrtf(var + 1e-5f);
            int j = jb + (jg << 3) + jj;
            float4 o4;
            o4.x = fmaf((a.x - mean) * rstd, g4.x, be4.x);
            o4.y = fmaf((a.y - mean) * rstd, g4.y, be4.y);
            o4.z = fmaf((a.z - mean) * rstd, g4.z, be4.z);
            o4.w = fmaf((a.w - mean) * rstd, g4.w, be4.w);
            *(float4*)(out + (((size_t)i << 10) + j) * DP + (pg << 2)) = o4;
        }
    }
}

extern "C" void kernel_launch(void* const* d_in, const int* in_sizes, int n_in,
                              void* d_out, int out_size, void* d_ws, size_t ws_size,
                              hipStream_t stream) {
    const float* single_a = (const float*)d_in[0];
    const float* single_b = (const float*)d_in[1];
    const float* x_a      = (const float*)d_in[2];
    const float* x_b      = (const float*)d_in[3];
    const float* W_left   = (const float*)d_in[4];
    const float* b_left   = (const float*)d_in[5];
    const float* W_right  = (const float*)d_in[6];
    const float* b_right  = (const float*)d_in[7];
    const float* W_outer  = (const float*)d_in[8];
    const float* b_outer  = (const float*)d_in[9];
    const float* W_dist   = (const float*)d_in[10];
    const float* b_dist   = (const float*)d_in[11];
    const float* gamma    = (const float*)d_in[12];
    const float* beta     = (const float*)d_in[13];
    const float* centers  = (const float*)d_in[14];
    float* out = (float*)d_out;

    float* left  = (float*)d_ws;            // [1024][32]
    float* right = left + (size_t)NA * RANK; // [1024][32]

    proj_kernel<<<NA / 8, 256, 0, stream>>>(single_a, W_left, b_left, left);
    proj_kernel<<<NB / 8, 256, 0, stream>>>(single_b, W_right, b_right, right);

    hipFuncSetAttribute((const void*)pair_kernel,
                        hipFuncAttributeMaxDynamicSharedMemorySize, SMEM_BYTES);
    pair_kernel<<<NA, 256, SMEM_BYTES, stream>>>(left, right, x_a, x_b,
                                                 W_outer, b_outer, W_dist, b_dist,
                                                 gamma, beta, centers, out);
}

// Round 6
// 680.738 us; speedup vs baseline: 1.3719x; 1.3719x over previous
//
#include <hip/hip_runtime.h>
#include <hip/hip_bf16.h>
#include <math.h>

#define NA 1024
#define NB 1024
#define DS 512
#define RANK 32
#define DP 128
#define NRBF 64
#define PADK 104    // 96 k padded; row = 208 B (16B-aligned, ~2-way bank aliasing)

typedef short bf16x8 __attribute__((ext_vector_type(8)));
typedef float f32x4 __attribute__((ext_vector_type(4)));
typedef unsigned short ushort8 __attribute__((ext_vector_type(8)));

static __device__ __forceinline__ unsigned short f2b(float f) {
    unsigned int u = __float_as_uint(f);
    unsigned int r = (u + 0x7FFFu + ((u >> 16) & 1u)) >> 16;   // RNE
    return (unsigned short)r;
}

// ---------------- proj (fp32 out): out[i][r] = b[r] + single[i]·W[r]
__global__ void proj_f32_kernel(const float* __restrict__ in, const float* __restrict__ W,
                                const float* __restrict__ b, float* __restrict__ out) {
    int t = threadIdx.x;
    int r = t & 31;
    int row = blockIdx.x * 8 + (t >> 5);
    const float4* in4 = (const float4*)(in + (size_t)row * DS);
    const float4* w4  = (const float4*)(W + (size_t)r * DS);
    float s = 0.f;
#pragma unroll 8
    for (int d = 0; d < DS / 4; ++d) {
        float4 a = in4[d], w = w4[d];
        s = fmaf(a.x, w.x, s); s = fmaf(a.y, w.y, s);
        s = fmaf(a.z, w.z, s); s = fmaf(a.w, w.w, s);
    }
    out[row * RANK + r] = s + b[r];
}

// ---------------- proj (bf16 out) for the right side
__global__ void proj_b16_kernel(const float* __restrict__ in, const float* __restrict__ W,
                                const float* __restrict__ b, unsigned short* __restrict__ out) {
    int t = threadIdx.x;
    int r = t & 31;
    int row = blockIdx.x * 8 + (t >> 5);
    const float4* in4 = (const float4*)(in + (size_t)row * DS);
    const float4* w4  = (const float4*)(W + (size_t)r * DS);
    float s = 0.f;
#pragma unroll 8
    for (int d = 0; d < DS / 4; ++d) {
        float4 a = in4[d], w = w4[d];
        s = fmaf(a.x, w.x, s); s = fmaf(a.y, w.y, s);
        s = fmaf(a.z, w.z, s); s = fmaf(a.w, w.w, s);
    }
    out[row * RANK + r] = f2b(s + b[r]);
}

// ---------------- lw[i][p][s] = sum_r left[i][r] * W_outer[p][r*32+s]  (bf16 out)
__global__ void __launch_bounds__(256) lw_kernel(const float* __restrict__ left,
                                                 const float* __restrict__ W_outer,
                                                 unsigned short* __restrict__ lw_bf) {
    __shared__ float Ls[2][RANK];
    int t = threadIdx.x;
    int i0 = blockIdx.x * 2;
    if (t < 64) Ls[t >> 5][t & 31] = left[(i0 + (t >> 5)) * RANK + (t & 31)];
    __syncthreads();
    int s = t & 31, pg = t >> 5;              // pg 0..7 -> p = pg*16 + pp
    float a0[16], a1[16];
#pragma unroll
    for (int pp = 0; pp < 16; ++pp) { a0[pp] = 0.f; a1[pp] = 0.f; }
#pragma unroll 4
    for (int r = 0; r < RANK; ++r) {
        float l0 = Ls[0][r], l1 = Ls[1][r];
        const float* wp = W_outer + (size_t)(pg * 16) * (RANK * RANK) + r * RANK + s;
#pragma unroll
        for (int pp = 0; pp < 16; ++pp) {
            float wv = wp[(size_t)pp * (RANK * RANK)];
            a0[pp] = fmaf(l0, wv, a0[pp]);
            a1[pp] = fmaf(l1, wv, a1[pp]);
        }
    }
#pragma unroll
    for (int pp = 0; pp < 16; ++pp) {
        int p = pg * 16 + pp;
        lw_bf[((size_t)i0 * DP + p) * RANK + s]       = f2b(a0[pp]);
        lw_bf[((size_t)(i0 + 1) * DP + p) * RANK + s] = f2b(a1[pp]);
    }
}

// ---------------- tiny prep: W_dist -> bf16, bsum = b_outer + b_dist
__global__ void prep_kernel(const float* __restrict__ W_dist, const float* __restrict__ b_outer,
                            const float* __restrict__ b_dist, unsigned short* __restrict__ wd_bf,
                            float* __restrict__ bsum) {
    int idx = blockIdx.x * 256 + threadIdx.x;
    if (idx < DP * NRBF) wd_bf[idx] = f2b(W_dist[idx]);
    if (idx < DP) bsum[idx] = b_outer[idx] + b_dist[idx];
}

// ---------------- pair kernel: block = (i, 64-j tile); 4 waves; MFMA 16x16x32 bf16
__global__ void __launch_bounds__(256) pair_kernel(
    const unsigned short* __restrict__ lw_bf, const unsigned short* __restrict__ right_bf,
    const unsigned short* __restrict__ wd_bf, const float* __restrict__ bsum,
    const float* __restrict__ x_a, const float* __restrict__ x_b,
    const float* __restrict__ gamma, const float* __restrict__ beta,
    const float* __restrict__ centers, float* __restrict__ out) {
    __shared__ unsigned short sU[DP * PADK];   // Ut[p][k]: k<32 = lw_t(i), k 32..95 = W_dist^T
    __shared__ unsigned short sV[64 * PADK];   // V[jl][k]: k<32 = right, k 32..95 = rbf

    const int t = threadIdx.x;
    const int bx = blockIdx.x;
    const int i = bx >> 4;
    const int jb = (bx & 15) << 6;

    // ---- stage Ut k<32 (512 x 16B, linear from lw_bf row i)
    {
        const ushort8* src = (const ushort8*)(lw_bf + (size_t)i * DP * RANK);
#pragma unroll
        for (int c = t; c < 512; c += 256) {
            ushort8 v = src[c];
            int p = c >> 2, ch = c & 3;
            *(ushort8*)(&sU[p * PADK + ch * 8]) = v;
        }
    }
    // ---- stage Ut k 32..95 (1024 x 16B from wd_bf[128][64])
    {
        const ushort8* src = (const ushort8*)wd_bf;
#pragma unroll
        for (int c = t; c < 1024; c += 256) {
            ushort8 v = src[c];
            int p = c >> 3, ch = c & 7;
            *(ushort8*)(&sU[p * PADK + RANK + ch * 8]) = v;
        }
    }
    // ---- stage V right part (256 x 16B)
    {
        const ushort8* src = (const ushort8*)(right_bf + (size_t)jb * RANK);
        ushort8 v = src[t];
        int jl = t >> 2, ch = t & 3;
        *(ushort8*)(&sV[jl * PADK + ch * 8]) = v;
    }
    // ---- V rbf part: thread owns (jl, 16-k group)
    {
        int jl = t & 63, kg = t >> 6;
        int j = jb + jl;
        float dx = x_a[i * 3 + 0] - x_b[j * 3 + 0];
        float dy = x_a[i * 3 + 1] - x_b[j * 3 + 1];
        float dz = x_a[i * 3 + 2] - x_b[j * 3 + 2];
        float d = sqrtf(fmaf(dx, dx, fmaf(dy, dy, dz * dz)));
        ushort8 r0, r1;
#pragma unroll
        for (int kk = 0; kk < 8; ++kk) {
            float u = d - centers[kg * 16 + kk];
            r0[kk] = f2b(__expf(-10.24f * u * u));   // 1/sigma = (64/20)^2
        }
#pragma unroll
        for (int kk = 0; kk < 8; ++kk) {
            float u = d - centers[kg * 16 + 8 + kk];
            r1[kk] = f2b(__expf(-10.24f * u * u));
        }
        *(ushort8*)(&sV[jl * PADK + RANK + kg * 16]) = r0;
        *(ushort8*)(&sV[jl * PADK + RANK + kg * 16 + 8]) = r1;
    }
    __syncthreads();

    const int l = t & 63, w = t >> 6;
    const int ar = l & 15;          // A/B row|col within tile
    const int kq = l >> 4;          // k-group 0..3
    const int k8 = kq * 8;

    f32x4 acc[8];
#pragma unroll
    for (int pt = 0; pt < 8; ++pt)
        acc[pt] = *(const f32x4*)(bsum + pt * 16 + kq * 4);

#pragma unroll
    for (int ks = 0; ks < 3; ++ks) {
        bf16x8 b = *(const bf16x8*)(&sV[(w * 16 + ar) * PADK + ks * 32 + k8]);
#pragma unroll
        for (int pt = 0; pt < 8; ++pt) {
            bf16x8 a = *(const bf16x8*)(&sU[(pt * 16 + ar) * PADK + ks * 32 + k8]);
            acc[pt] = __builtin_amdgcn_mfma_f32_16x16x32_bf16(a, b, acc[pt], 0, 0, 0);
        }
    }

    // ---- LayerNorm over 128 p (32 per lane, x4 lanes sharing a j) + store
    float s1 = 0.f, s2 = 0.f;
#pragma unroll
    for (int pt = 0; pt < 8; ++pt)
#pragma unroll
        for (int e = 0; e < 4; ++e) {
            float v = acc[pt][e];
            s1 += v;
            s2 = fmaf(v, v, s2);
        }
    s1 += __shfl_xor(s1, 16); s2 += __shfl_xor(s2, 16);
    s1 += __shfl_xor(s1, 32); s2 += __shfl_xor(s2, 32);
    float mean = s1 * (1.f / 128.f);
    float var = fmaf(s2, 1.f / 128.f, -mean * mean);
    float rstd = rsqrtf(var + 1e-5f);

    int j = jb + w * 16 + ar;
    float* orow = out + ((size_t)(i << 10) + j) * DP;
#pragma unroll
    for (int pt = 0; pt < 8; ++pt) {
        int pb = pt * 16 + kq * 4;
        float4 g = *(const float4*)(gamma + pb);
        float4 be = *(const float4*)(beta + pb);
        float4 o;
        o.x = fmaf((acc[pt][0] - mean) * rstd, g.x, be.x);
        o.y = fmaf((acc[pt][1] - mean) * rstd, g.y, be.y);
        o.z = fmaf((acc[pt][2] - mean) * rstd, g.z, be.z);
        o.w = fmaf((acc[pt][3] - mean) * rstd, g.w, be.w);
        *(float4*)(orow + pb) = o;
    }
}

extern "C" void kernel_launch(void* const* d_in, const int* in_sizes, int n_in,
                              void* d_out, int out_size, void* d_ws, size_t ws_size,
                              hipStream_t stream) {
    const float* single_a = (const float*)d_in[0];
    const float* single_b = (const float*)d_in[1];
    const float* x_a      = (const float*)d_in[2];
    const float* x_b      = (const float*)d_in[3];
    const float* W_left   = (const float*)d_in[4];
    const float* b_left   = (const float*)d_in[5];
    const float* W_right  = (const float*)d_in[6];
    const float* b_right  = (const float*)d_in[7];
    const float* W_outer  = (const float*)d_in[8];
    const float* b_outer  = (const float*)d_in[9];
    const float* W_dist   = (const float*)d_in[10];
    const float* b_dist   = (const float*)d_in[11];
    const float* gamma    = (const float*)d_in[12];
    const float* beta     = (const float*)d_in[13];
    const float* centers  = (const float*)d_in[14];
    float* out = (float*)d_out;

    // ws layout (all 16B aligned)
    float* left = (float*)d_ws;                                  // 1024*32 f32   = 128 KB
    unsigned short* right_bf = (unsigned short*)(left + NA * RANK);     // 64 KB
    unsigned short* lw_bf = right_bf + NB * RANK;                       // 1024*128*32 bf16 = 8 MB
    unsigned short* wd_bf = lw_bf + (size_t)NA * DP * RANK;             // 16 KB
    float* bsum = (float*)(wd_bf + DP * NRBF);                          // 512 B

    proj_f32_kernel<<<NA / 8, 256, 0, stream>>>(single_a, W_left, b_left, left);
    proj_b16_kernel<<<NB / 8, 256, 0, stream>>>(single_b, W_right, b_right, right_bf);
    lw_kernel<<<NA / 2, 256, 0, stream>>>(left, W_outer, lw_bf);
    prep_kernel<<<32, 256, 0, stream>>>(W_dist, b_outer, b_dist, wd_bf, bsum);
    pair_kernel<<<NA * 16, 256, 0, stream>>>(lw_bf, right_bf, wd_bf, bsum,
                                             x_a, x_b, gamma, beta, centers, out);
}